// Round 1
// baseline (277.849 us; speedup 1.0000x reference)
//
#include <hip/hip_runtime.h>
#include <hip/hip_bf16.h>
#include <math.h>

#define SEQ 4096
#define DM  768
#define NH  12
#define HD  64
#define PER ((size_t)NH * SEQ * HD)       // 3,145,728
#define XN  ((size_t)SEQ * DM)
#define WN  ((size_t)DM * DM)

typedef __attribute__((ext_vector_type(8))) short bf16x8;   // MFMA A/B frag
typedef __attribute__((ext_vector_type(4))) short s16x4;
typedef __attribute__((ext_vector_type(4))) float f32x4;    // MFMA C/D frag

#define MFMA(a, b, c) __builtin_amdgcn_mfma_f32_16x16x32_bf16((a), (b), (c), 0, 0, 0)

#if __has_builtin(__builtin_amdgcn_exp2f)
#define EXP2(x) __builtin_amdgcn_exp2f(x)
#else
#define EXP2(x) exp2f(x)
#endif

// XOR-swizzled 64-wide bf16 LDS tile, 16B blocks (conflict-free b128).
#define SWZ(row, blk) (((row) << 6) + ((((blk) ^ ((row) & 7))) << 3))

// fast RTNE fp32->bf16 (finite values only)
__device__ __forceinline__ unsigned short f2b(float f) {
    unsigned int u = __float_as_uint(f);
    u += 0x7FFFu + ((u >> 16) & 1u);
    return (unsigned short)(u >> 16);
}

// ---------------------------------------------------------------------------
// Prep: ONE kernel converts x + 4 weights fp32->bf16 and fills the RoPE table.
// ---------------------------------------------------------------------------
__global__ __launch_bounds__(256) void prep_kernel(
    const float* __restrict__ x,  const float* __restrict__ wq,
    const float* __restrict__ wk, const float* __restrict__ wv,
    const float* __restrict__ wo,
    unsigned short* __restrict__ dstbase, float2* __restrict__ rope)
{
    const float* srcs[5] = {x, wq, wk, wv, wo};
    const size_t n4s[5]  = {XN / 4, WN / 4, WN / 4, WN / 4, WN / 4};
    unsigned short* d = dstbase;
    for (int rg = 0; rg < 5; ++rg) {
        const float4* s4 = (const float4*)srcs[rg];
        s16x4* d4 = (s16x4*)d;
        for (size_t i = (size_t)blockIdx.x * 256 + threadIdx.x; i < n4s[rg];
             i += (size_t)gridDim.x * 256) {
            const float4 v = s4[i];
            s16x4 p;
            p.x = (short)f2b(v.x); p.y = (short)f2b(v.y);
            p.z = (short)f2b(v.z); p.w = (short)f2b(v.w);
            d4[i] = p;
        }
        d += n4s[rg] * 4;
    }
    for (int g = blockIdx.x * 256 + threadIdx.x; g < 131072; g += gridDim.x * 256) {
        const int row = g >> 5, fi = g & 31;
        const float invf = expf(-(float)fi * 0.28782313662425576f);
        float sn, cs;
        sincosf((float)row * invf, &sn, &cs);
        rope[row * 32 + fi] = make_float2(cs, sn);
    }
}

// ---------------------------------------------------------------------------
// K1: QKV projection (x @ W.T, MFMA) — unchanged.
// ---------------------------------------------------------------------------
__global__ __launch_bounds__(256) void qkv_mfma(
    const float* __restrict__ x,  const unsigned short* __restrict__ xb,
    const float* __restrict__ Wq, const float* __restrict__ Wk, const float* __restrict__ Wv,
    const unsigned short* __restrict__ Wqb, const unsigned short* __restrict__ Wkb,
    const unsigned short* __restrict__ Wvb,
    const float2* __restrict__ rope,
    unsigned short* __restrict__ Qo, unsigned short* __restrict__ Ko,
    unsigned short* __restrict__ Vo, int fast)
{
    __shared__ __align__(16) unsigned short Xs[2][4096];
    __shared__ __align__(16) unsigned short Ws[2][4096];
    __shared__ unsigned short VL[64 * 66];

    const int t    = threadIdx.x;
    const int w    = t >> 6;
    const int lane = t & 63;
    const int quad = lane >> 4;
    const int l16  = lane & 15;

    const int nt_b = blockIdx.y;
    const float* W; const unsigned short* Wb; int region;
    if (nt_b < 12)      { W = Wq; Wb = Wqb; region = 0; }
    else if (nt_b < 24) { W = Wk; Wb = Wkb; region = 1; }
    else                { W = Wv; Wb = Wvb; region = 2; }
    const int h  = nt_b % 12;
    const int s0 = blockIdx.x * 64;
    const int n0 = h * 64;

    f32x4 acc[4] = {{0,0,0,0},{0,0,0,0},{0,0,0,0},{0,0,0,0}};
    const int prow = t >> 3, pblk = t & 7;

    bf16x8 xr0, xr1, wr0, wr1;
    if (fast) {
        xr0 = *(const bf16x8*)&xb[(size_t)(s0 + prow) * DM + pblk * 8];
        xr1 = *(const bf16x8*)&xb[(size_t)(s0 + prow + 32) * DM + pblk * 8];
        wr0 = *(const bf16x8*)&Wb[(size_t)(n0 + prow) * DM + pblk * 8];
        wr1 = *(const bf16x8*)&Wb[(size_t)(n0 + prow + 32) * DM + pblk * 8];
        *(bf16x8*)&Xs[0][SWZ(prow, pblk)]      = xr0;
        *(bf16x8*)&Xs[0][SWZ(prow + 32, pblk)] = xr1;
        *(bf16x8*)&Ws[0][SWZ(prow, pblk)]      = wr0;
        *(bf16x8*)&Ws[0][SWZ(prow + 32, pblk)] = wr1;
    } else {
        for (int e = t; e < 1024; e += 256) {
            const int row = e >> 4, c4 = e & 15;
            const int off = SWZ(row, c4 >> 1) + (c4 & 1) * 4;
            const float4 xv = *(const float4*)&x[(size_t)(s0 + row) * DM + c4 * 4];
            s16x4 px; px.x = (short)f2b(xv.x); px.y = (short)f2b(xv.y);
            px.z = (short)f2b(xv.z); px.w = (short)f2b(xv.w);
            *(s16x4*)&Xs[0][off] = px;
            const float4 wv = *(const float4*)&W[(size_t)(n0 + row) * DM + c4 * 4];
            s16x4 pw; pw.x = (short)f2b(wv.x); pw.y = (short)f2b(wv.y);
            pw.z = (short)f2b(wv.z); pw.w = (short)f2b(wv.w);
            *(s16x4*)&Ws[0][off] = pw;
        }
    }
    __syncthreads();

    for (int kt = 0; kt < 12; ++kt) {
        const unsigned short* Xb  = Xs[kt & 1];
        const unsigned short* Wbt = Ws[kt & 1];
        if (fast && kt < 11) {
            const int k0 = (kt + 1) * 64;
            xr0 = *(const bf16x8*)&xb[(size_t)(s0 + prow) * DM + k0 + pblk * 8];
            xr1 = *(const bf16x8*)&xb[(size_t)(s0 + prow + 32) * DM + k0 + pblk * 8];
            wr0 = *(const bf16x8*)&Wb[(size_t)(n0 + prow) * DM + k0 + pblk * 8];
            wr1 = *(const bf16x8*)&Wb[(size_t)(n0 + prow + 32) * DM + k0 + pblk * 8];
        }
        const bf16x8 a0 = *(const bf16x8*)&Xb[SWZ(16 * w + l16, quad)];
        const bf16x8 a1 = *(const bf16x8*)&Xb[SWZ(16 * w + l16, 4 + quad)];
        #pragma unroll
        for (int nt = 0; nt < 4; ++nt) {
            const bf16x8 b0 = *(const bf16x8*)&Wbt[SWZ(16 * nt + l16, quad)];
            const bf16x8 b1 = *(const bf16x8*)&Wbt[SWZ(16 * nt + l16, 4 + quad)];
            acc[nt] = MFMA(a0, b0, acc[nt]);
            acc[nt] = MFMA(a1, b1, acc[nt]);
        }
        if (kt < 11) {
            const int nb = (kt + 1) & 1;
            if (fast) {
                *(bf16x8*)&Xs[nb][SWZ(prow, pblk)]      = xr0;
                *(bf16x8*)&Xs[nb][SWZ(prow + 32, pblk)] = xr1;
                *(bf16x8*)&Ws[nb][SWZ(prow, pblk)]      = wr0;
                *(bf16x8*)&Ws[nb][SWZ(prow + 32, pblk)] = wr1;
            } else {
                const int k0 = (kt + 1) * 64;
                for (int e = t; e < 1024; e += 256) {
                    const int row = e >> 4, c4 = e & 15;
                    const int off = SWZ(row, c4 >> 1) + (c4 & 1) * 4;
                    const float4 xv = *(const float4*)&x[(size_t)(s0 + row) * DM + k0 + c4 * 4];
                    s16x4 px; px.x = (short)f2b(xv.x); px.y = (short)f2b(xv.y);
                    px.z = (short)f2b(xv.z); px.w = (short)f2b(xv.w);
                    *(s16x4*)&Xs[nb][off] = px;
                    const float4 wv = *(const float4*)&W[(size_t)(n0 + row) * DM + k0 + c4 * 4];
                    s16x4 pw; pw.x = (short)f2b(wv.x); pw.y = (short)f2b(wv.y);
                    pw.z = (short)f2b(wv.z); pw.w = (short)f2b(wv.w);
                    *(s16x4*)&Ws[nb][off] = pw;
                }
            }
        }
        __syncthreads();
    }

    const size_t headoff = (size_t)h * SEQ * HD;
    if (region <= 1) {
        unsigned short* dst = (region == 0) ? Qo : Ko;
        const float qsc = (region == 0) ? 0.18033688011112042f : 1.0f;   // 0.125*log2e
        #pragma unroll
        for (int nt = 0; nt < 4; ++nt)
            #pragma unroll
            for (int r = 0; r < 4; ++r) {
                const int srow = s0 + 16 * w + quad * 4 + r;
                const int d  = nt * 16 + l16;
                const int fi = d >> 1;
                const float own = acc[nt][r] * qsc;
                const float oth = __shfl_xor(own, 1);
                float cs, sn;
                if (fast) {
                    const float2 t2 = rope[srow * 32 + fi];
                    cs = t2.x; sn = t2.y;
                } else {
                    const float invf = expf(-(float)fi * 0.28782313662425576f);
                    sincosf((float)srow * invf, &sn, &cs);
                }
                const float val = (d & 1) ? (oth * sn + own * cs)
                                          : (own * cs - oth * sn);
                dst[headoff + (size_t)srow * HD + ((d & 1) ? 32 : 0) + fi] = f2b(val);
            }
    } else {
        #pragma unroll
        for (int nt = 0; nt < 4; ++nt)
            #pragma unroll
            for (int r = 0; r < 4; ++r)
                VL[(nt * 16 + l16) * 66 + 16 * w + quad * 4 + r] = f2b(acc[nt][r]);
        __syncthreads();
        for (int e = t; e < 2048; e += 256) {
            const int d = e >> 5, sp = e & 31;
            const unsigned int v = (unsigned int)VL[d * 66 + 2 * sp] |
                                   ((unsigned int)VL[d * 66 + 2 * sp + 1] << 16);
            *(unsigned int*)&Vo[headoff + (size_t)d * SEQ + s0 + 2 * sp] = v;
        }
    }
}

// ---------------------------------------------------------------------------
// K2: causal flash attention, BARRIER-FREE main loop (round 9 restructure).
//
// Insight: each wave only ever consumes ITS OWN 32 keys' worth of K and V,
// and those fragments are contiguous, 16B-aligned bf16x8 chunks of global
// memory. So the old Kst/Vt LDS staging (32KB LDS + 16 ds_write_b128 + two
// __syncthreads per chunk) was a layout no-op. This version loads K/V frags
// straight from global, keeps only the per-wave P strip in LDS, and has ZERO
// barriers in the main loop: the 4 waves of a block run as independent
// streams (plus up to 3 blocks/CU), which is what the 12% occupancy / 13%
// MfmaUtil lockstep was starving.  Software pipeline: V frags are loaded one
// chunk ahead (consumed only after QK+exp2 ~300cy later); next-chunk K frags
// issue right after the QK phase.
// Grid unchanged: (96,12) split / (64,12) fallback.
// ---------------------------------------------------------------------------
__global__ __launch_bounds__(256, 3) void attn_mfma(
    const unsigned short* __restrict__ Q,    // [h][seq][64], pre-scaled
    const unsigned short* __restrict__ K,    // [h][seq][64]
    const unsigned short* __restrict__ V,    // [h][64][seq]  (transposed)
    unsigned short* __restrict__ O,          // [4096][768]
    float* __restrict__ Part)                // [384][2][4160] fp32 partials
{
    // LDS: per-wave P strips (64x40 u16 each) during the loop; reduction
    // buffers for the tail. ACC overlays the strips (dead by then).
    __shared__ __align__(16) unsigned char SM[39936];
    unsigned short* Ps = (unsigned short*)SM;            // 4 strips 64x40, 20480B
    float* ACC  = (float*)SM;                            // 64x72 f32, 18432B
    float* ACC2 = (float*)(SM + 20480);                  // 18432B
    float* Lx   = (float*)(SM + 38912);                  // 1024B

    const int h  = blockIdx.y;
    const int xx = blockIdx.x;
    int i, kstart, nch, domask, partial, pslice;
    if (gridDim.x == 96) {
        if (xx < 64) {
            i = 63 - xx; kstart = 0;
            const int full = ((i * 64 + 63) >> 7) + 1;
            nch = full < 16 ? full : 16;
            domask  = (i <= 31);
            partial = (i >= 32); pslice = 0;
        } else {
            i = 127 - xx; kstart = 2048;
            nch = ((i * 64 + 63 - 2048) >> 7) + 1;
            domask = 1; partial = 1; pslice = 1;
        }
    } else {
        i = 63 - xx; kstart = 0;
        nch = ((i * 64 + 63) >> 7) + 1;
        domask = 1; partial = 0; pslice = 0;
    }
    const int q0 = i * 64;

    const int t    = threadIdx.x;
    const int w    = t >> 6;
    const int lane = t & 63;
    const int quad = lane >> 4;
    const int l16  = lane & 15;
    const size_t headoff = (size_t)h * SEQ * HD;

    const unsigned short* Qg = Q + headoff;
    const unsigned short* Kg = K + headoff;
    const unsigned short* Vg = V + headoff;

    // ---- Q fragments straight from global (A-frag: row=q, 16B chunks) ----
    bf16x8 aQ[4][2];
    #pragma unroll
    for (int qt = 0; qt < 4; ++qt)
        #pragma unroll
        for (int hh = 0; hh < 2; ++hh)
            aQ[qt][hh] = *(const bf16x8*)
                &Qg[(size_t)(q0 + 16 * qt + l16) * HD + (4 * hh + quad) * 8];

    // ---- prologue: K + V fragments for chunk 0 ----
    bf16x8 kf00, kf01, kf10, kf11, vf[4];
    {
        const size_t kr = (size_t)(kstart + 32 * w + l16) * HD + quad * 8;
        kf00 = *(const bf16x8*)&Kg[kr];
        kf01 = *(const bf16x8*)&Kg[kr + 32];
        kf10 = *(const bf16x8*)&Kg[kr + 16 * HD];
        kf11 = *(const bf16x8*)&Kg[kr + 16 * HD + 32];
        #pragma unroll
        for (int dt = 0; dt < 4; ++dt)
            vf[dt] = *(const bf16x8*)
                &Vg[(size_t)(16 * dt + l16) * SEQ + kstart + (4 * w + quad) * 8];
    }

    bf16x8 ones;
    #pragma unroll
    for (int ii = 0; ii < 8; ++ii) ones[ii] = (short)0x3F80;

    f32x4 oT[4][4];
    #pragma unroll
    for (int dt = 0; dt < 4; ++dt)
        #pragma unroll
        for (int qt = 0; qt < 4; ++qt) oT[dt][qt] = (f32x4){0,0,0,0};
    f32x4 lT[4] = {{0,0,0,0},{0,0,0,0},{0,0,0,0},{0,0,0,0}};

    unsigned short* usp = Ps + w * 2560;

    for (int c = 0; c < nch; ++c) {
        const int k0 = kstart + c * 128;
        const int last = (c == nch - 1);

        // ---- QK^T + mask + exp2 + P-strip store (qt-major: small sC live range)
        #pragma unroll
        for (int qt = 0; qt < 4; ++qt) {
            f32x4 s0 = (f32x4){0,0,0,0}, s1 = (f32x4){0,0,0,0};
            #pragma unroll
            for (int hh = 0; hh < 2; ++hh) {
                const bf16x8 a = aQ[qt][hh];
                s0 = MFMA(a, (hh ? kf01 : kf00), s0);
                s1 = MFMA(a, (hh ? kf11 : kf10), s1);
            }
            if (domask && last) {
                const int key0 = k0 + 32 * w + l16;
                #pragma unroll
                for (int r = 0; r < 4; ++r) {
                    const int qrow = q0 + 16 * qt + 4 * quad + r;
                    if (key0 > qrow)      s0[r] = -1e30f;
                    if (key0 + 16 > qrow) s1[r] = -1e30f;
                }
            }
            #pragma unroll
            for (int r = 0; r < 4; ++r) {
                const int row = (16 * qt + 4 * quad + r) * 40;
                usp[row + l16]      = f2b(EXP2(s0[r]));
                usp[row + 16 + l16] = f2b(EXP2(s1[r]));
            }
        }

        // ---- prefetch next chunk's K frags (consumed at next QK; covered by PV)
        if (c + 1 < nch) {
            const size_t kr = (size_t)(k0 + 128 + 32 * w + l16) * HD + quad * 8;
            kf00 = *(const bf16x8*)&Kg[kr];
            kf01 = *(const bf16x8*)&Kg[kr + 32];
            kf10 = *(const bf16x8*)&Kg[kr + 16 * HD];
            kf11 = *(const bf16x8*)&Kg[kr + 16 * HD + 32];
        }

        asm volatile("s_waitcnt lgkmcnt(0)" ::: "memory");

        // ---- PV + row-sum (wave-private strip, no barrier needed) ----
        __builtin_amdgcn_s_setprio(1);
        #pragma unroll
        for (int qt = 0; qt < 4; ++qt) {
            const bf16x8 bP = *(const bf16x8*)&usp[(16 * qt + l16) * 40 + quad * 8];
            lT[qt] = MFMA(ones, bP, lT[qt]);
            oT[0][qt] = MFMA(vf[0], bP, oT[0][qt]);
            oT[1][qt] = MFMA(vf[1], bP, oT[1][qt]);
            oT[2][qt] = MFMA(vf[2], bP, oT[2][qt]);
            oT[3][qt] = MFMA(vf[3], bP, oT[3][qt]);
        }
        __builtin_amdgcn_s_setprio(0);

        // ---- prefetch next chunk's V frags (consumed after next QK+exp2) ----
        if (c + 1 < nch) {
            const int kn = k0 + 128;
            #pragma unroll
            for (int dt = 0; dt < 4; ++dt)
                vf[dt] = *(const bf16x8*)
                    &Vg[(size_t)(16 * dt + l16) * SEQ + kn + (4 * w + quad) * 8];
        }
    }

    // ---- cross-wave reduction of O^T and l (strips dead; ACC overlays Ps) ----
    __syncthreads();
    if (w != 0 && quad == 0) {
        #pragma unroll
        for (int qt = 0; qt < 4; ++qt)
            Lx[w * 64 + 16 * qt + l16] = lT[qt][0];
    }
    if (w == 1) {
        #pragma unroll
        for (int dt = 0; dt < 4; ++dt)
            #pragma unroll
            for (int qt = 0; qt < 4; ++qt)
                *(f32x4*)&ACC[(16 * qt + l16) * 72 + 16 * dt + 4 * quad] = oT[dt][qt];
    }
    __syncthreads();
    if (w == 0) {
        #pragma unroll
        for (int dt = 0; dt < 4; ++dt)
            #pragma unroll
            for (int qt = 0; qt < 4; ++qt)
                oT[dt][qt] += *(const f32x4*)&ACC[(16 * qt + l16) * 72 + 16 * dt + 4 * quad];
    }
    if (w == 2) {
        #pragma unroll
        for (int dt = 0; dt < 4; ++dt)
            #pragma unroll
            for (int qt = 0; qt < 4; ++qt)
                *(f32x4*)&ACC2[(16 * qt + l16) * 72 + 16 * dt + 4 * quad] = oT[dt][qt];
    }
    __syncthreads();
    if (w == 0) {
        #pragma unroll
        for (int dt = 0; dt < 4; ++dt)
            #pragma unroll
            for (int qt = 0; qt < 4; ++qt)
                oT[dt][qt] += *(const f32x4*)&ACC2[(16 * qt + l16) * 72 + 16 * dt + 4 * quad];
    }
    if (w == 3) {
        #pragma unroll
        for (int dt = 0; dt < 4; ++dt)
            #pragma unroll
            for (int qt = 0; qt < 4; ++qt)
                *(f32x4*)&ACC[(16 * qt + l16) * 72 + 16 * dt + 4 * quad] = oT[dt][qt];
    }
    __syncthreads();
    if (w == 0) {
        float ls[4];
        #pragma unroll
        for (int qt = 0; qt < 4; ++qt) {
            #pragma unroll
            for (int dt = 0; dt < 4; ++dt)
                oT[dt][qt] += *(const f32x4*)&ACC[(16 * qt + l16) * 72 + 16 * dt + 4 * quad];
            ls[qt] = lT[qt][0] + Lx[64 + 16 * qt + l16] +
                     Lx[128 + 16 * qt + l16] + Lx[192 + 16 * qt + l16];
        }
        if (!partial) {
            #pragma unroll
            for (int qt = 0; qt < 4; ++qt) {
                const float inv = 1.0f / ls[qt];
                const size_t rowoff = (size_t)(q0 + 16 * qt + l16) * DM + h * HD;
                #pragma unroll
                for (int dt = 0; dt < 4; ++dt) {
                    ushort4 u;
                    u.x = f2b(oT[dt][qt][0] * inv);
                    u.y = f2b(oT[dt][qt][1] * inv);
                    u.z = f2b(oT[dt][qt][2] * inv);
                    u.w = f2b(oT[dt][qt][3] * inv);
                    *(ushort4*)&O[rowoff + 16 * dt + 4 * quad] = u;
                }
            }
        } else {
            // Partials in [q][d] layout matching the C-fragment:
            // oT[dt][qt][r] = O[q=16qt+l16][d=16dt+4quad+r].
            float* P = Part + (size_t)(((i - 32) * 12 + h) * 2 + pslice) * 4160;
            #pragma unroll
            for (int dt = 0; dt < 4; ++dt)
                #pragma unroll
                for (int qt = 0; qt < 4; ++qt)
                    *(f32x4*)&P[(16 * qt + l16) * 64 + 16 * dt + 4 * quad] = oT[dt][qt];
            if (quad == 0) {
                #pragma unroll
                for (int qt = 0; qt < 4; ++qt)
                    P[4096 + 16 * qt + l16] = ls[qt];
            }
        }
    }
}

// ---------------------------------------------------------------------------
// K2b: combine the two key-slices for q-tiles 32..63, normalize, write O.
// Grid (384): b -> (i = 32 + b/12, h = b%12). Partials are [q][d] fp32.
// ---------------------------------------------------------------------------
__global__ __launch_bounds__(256) void reduce_attn(
    const float* __restrict__ Part, unsigned short* __restrict__ O)
{
    const int b  = blockIdx.x;
    const int i  = 32 + b / 12, h = b % 12;
    const int q0 = i * 64;
    const float* P0 = Part + (size_t)(b * 2 + 0) * 4160;
    const float* P1 = Part + (size_t)(b * 2 + 1) * 4160;
    __shared__ float linv[64];
    const int t = threadIdx.x;
    if (t < 64) linv[t] = 1.0f / (P0[4096 + t] + P1[4096 + t]);
    __syncthreads();
    for (int idx = t; idx < 4096; idx += 256) {
        const int q = idx >> 6, d = idx & 63;
        const float v = (P0[q * 64 + d] + P1[q * 64 + d]) * linv[q];
        O[(size_t)(q0 + q) * DM + h * HD + d] = f2b(v);
    }
}

// ---------------------------------------------------------------------------
// K3: output projection out = A @ Wo.T + bo (MFMA) — unchanged.
// ---------------------------------------------------------------------------
__global__ __launch_bounds__(256) void proj_mfma(
    const unsigned short* __restrict__ A,
    const float* __restrict__ Wo, const unsigned short* __restrict__ Wob,
    const float* __restrict__ bo,
    float* __restrict__ out, int fast)
{
    __shared__ __align__(16) unsigned short Xs[2][4096];
    __shared__ __align__(16) unsigned short Ws[2][4096];

    const int t    = threadIdx.x;
    const int w    = t >> 6;
    const int lane = t & 63;
    const int quad = lane >> 4;
    const int l16  = lane & 15;
    const int s0 = blockIdx.x * 64;
    const int n0 = blockIdx.y * 64;
    const int prow = t >> 3, pblk = t & 7;

    f32x4 acc[4] = {{0,0,0,0},{0,0,0,0},{0,0,0,0},{0,0,0,0}};

    bf16x8 ar0, ar1, wr0, wr1;
    ar0 = *(const bf16x8*)&A[(size_t)(s0 + prow) * DM + pblk * 8];
    ar1 = *(const bf16x8*)&A[(size_t)(s0 + prow + 32) * DM + pblk * 8];
    *(bf16x8*)&Xs[0][SWZ(prow, pblk)]      = ar0;
    *(bf16x8*)&Xs[0][SWZ(prow + 32, pblk)] = ar1;
    if (fast) {
        wr0 = *(const bf16x8*)&Wob[(size_t)(n0 + prow) * DM + pblk * 8];
        wr1 = *(const bf16x8*)&Wob[(size_t)(n0 + prow + 32) * DM + pblk * 8];
        *(bf16x8*)&Ws[0][SWZ(prow, pblk)]      = wr0;
        *(bf16x8*)&Ws[0][SWZ(prow + 32, pblk)] = wr1;
    } else {
        for (int e = t; e < 1024; e += 256) {
            const int row = e >> 4, c4 = e & 15;
            const float4 wv = *(const float4*)&Wo[(size_t)(n0 + row) * DM + c4 * 4];
            s16x4 pw; pw.x = (short)f2b(wv.x); pw.y = (short)f2b(wv.y);
            pw.z = (short)f2b(wv.z); pw.w = (short)f2b(wv.w);
            *(s16x4*)&Ws[0][SWZ(row, c4 >> 1) + (c4 & 1) * 4] = pw;
        }
    }
    __syncthreads();

    for (int kt = 0; kt < 12; ++kt) {
        const unsigned short* Xb  = Xs[kt & 1];
        const unsigned short* Wbt = Ws[kt & 1];
        if (kt < 11) {
            const int k0 = (kt + 1) * 64;
            ar0 = *(const bf16x8*)&A[(size_t)(s0 + prow) * DM + k0 + pblk * 8];
            ar1 = *(const bf16x8*)&A[(size_t)(s0 + prow + 32) * DM + k0 + pblk * 8];
            if (fast) {
                wr0 = *(const bf16x8*)&Wob[(size_t)(n0 + prow) * DM + k0 + pblk * 8];
                wr1 = *(const bf16x8*)&Wob[(size_t)(n0 + prow + 32) * DM + k0 + pblk * 8];
            }
        }
        const bf16x8 a0 = *(const bf16x8*)&Xb[SWZ(16 * w + l16, quad)];
        const bf16x8 a1 = *(const bf16x8*)&Xb[SWZ(16 * w + l16, 4 + quad)];
        #pragma unroll
        for (int nt = 0; nt < 4; ++nt) {
            const bf16x8 b0 = *(const bf16x8*)&Wbt[SWZ(16 * nt + l16, quad)];
            const bf16x8 b1 = *(const bf16x8*)&Wbt[SWZ(16 * nt + l16, 4 + quad)];
            acc[nt] = MFMA(a0, b0, acc[nt]);
            acc[nt] = MFMA(a1, b1, acc[nt]);
        }
        if (kt < 11) {
            const int nb = (kt + 1) & 1;
            *(bf16x8*)&Xs[nb][SWZ(prow, pblk)]      = ar0;
            *(bf16x8*)&Xs[nb][SWZ(prow + 32, pblk)] = ar1;
            if (fast) {
                *(bf16x8*)&Ws[nb][SWZ(prow, pblk)]      = wr0;
                *(bf16x8*)&Ws[nb][SWZ(prow + 32, pblk)] = wr1;
            } else {
                const int k0 = (kt + 1) * 64;
                for (int e = t; e < 1024; e += 256) {
                    const int row = e >> 4, c4 = e & 15;
                    const float4 wv = *(const float4*)&Wo[(size_t)(n0 + row) * DM + k0 + c4 * 4];
                    s16x4 pw; pw.x = (short)f2b(wv.x); pw.y = (short)f2b(wv.y);
                    pw.z = (short)f2b(wv.z); pw.w = (short)f2b(wv.w);
                    *(s16x4*)&Ws[nb][SWZ(row, c4 >> 1) + (c4 & 1) * 4] = pw;
                }
            }
        }
        __syncthreads();
    }

    #pragma unroll
    for (int nt = 0; nt < 4; ++nt)
        #pragma unroll
        for (int r = 0; r < 4; ++r) {
            const int srow = s0 + 16 * w + quad * 4 + r;
            const int n    = n0 + nt * 16 + l16;
            out[(size_t)srow * DM + n] = acc[nt][r] + bo[n];
        }
}

// ---------------------------------------------------------------------------
extern "C" void kernel_launch(void* const* d_in, const int* in_sizes, int n_in,
                              void* d_out, int out_size, void* d_ws, size_t ws_size,
                              hipStream_t stream) {
    const float* x  = (const float*)d_in[0];
    const float* Wq = (const float*)d_in[2];
    const float* Wk = (const float*)d_in[3];
    const float* Wv = (const float*)d_in[4];
    const float* Wo = (const float*)d_in[5];
    const float* bo = (const float*)d_in[6];
    float* out = (float*)d_out;

    unsigned short* U  = (unsigned short*)d_ws;
    unsigned short* Qw = U;
    unsigned short* Kw = U + PER;
    unsigned short* Vw = U + 2 * PER;    // transposed [h][64][seq]
    unsigned short* Ow = U + 3 * PER;    // [4096][768]
    unsigned short* xb  = U + 4 * PER;
    unsigned short* Wqb = xb + XN;
    unsigned short* Wkb = Wqb + WN;
    unsigned short* Wvb = Wkb + WN;
    unsigned short* Wob = Wvb + WN;
    float2* rope = (float2*)(Wob + WN);  // [4096][32]
    float*  part = (float*)(rope + 4096 * 32);   // [384][2][4160] fp32
    const size_t need  = (char*)part - (char*)d_ws;
    const size_t need2 = need + (size_t)384 * 2 * 4160 * 4;
    const int fast  = (ws_size >= need)  ? 1 : 0;
    const int split = (ws_size >= need2) ? 1 : 0;

    if (fast)
        prep_kernel<<<1024, 256, 0, stream>>>(x, Wq, Wk, Wv, Wo, xb, rope);
    qkv_mfma<<<dim3(SEQ / 64, 36), 256, 0, stream>>>(
        x, xb, Wq, Wk, Wv, Wqb, Wkb, Wvb, rope, Qw, Kw, Vw, fast);
    if (split) {
        attn_mfma<<<dim3(96, NH), 256, 0, stream>>>(Qw, Kw, Vw, Ow, part);
        reduce_attn<<<dim3(384), 256, 0, stream>>>(part, Ow);
    } else {
        attn_mfma<<<dim3(64, NH), 256, 0, stream>>>(Qw, Kw, Vw, Ow, part);
    }
    proj_mfma<<<dim3(SEQ / 64, DM / 64), 256, 0, stream>>>(Ow, Wo, Wob, bo, out, fast);
}

// Round 2
// 230.898 us; speedup vs baseline: 1.2033x; 1.2033x over previous
//
#include <hip/hip_runtime.h>
#include <hip/hip_bf16.h>
#include <math.h>

#define SEQ 4096
#define DM  768
#define NH  12
#define HD  64
#define PER ((size_t)NH * SEQ * HD)       // 3,145,728
#define XN  ((size_t)SEQ * DM)
#define WN  ((size_t)DM * DM)

typedef __attribute__((ext_vector_type(8))) short bf16x8;   // MFMA A/B frag
typedef __attribute__((ext_vector_type(4))) short s16x4;
typedef __attribute__((ext_vector_type(4))) float f32x4;    // MFMA C/D frag

#define MFMA(a, b, c) __builtin_amdgcn_mfma_f32_16x16x32_bf16((a), (b), (c), 0, 0, 0)

#if __has_builtin(__builtin_amdgcn_exp2f)
#define EXP2(x) __builtin_amdgcn_exp2f(x)
#else
#define EXP2(x) exp2f(x)
#endif

// XOR-swizzled 64-wide bf16 LDS tile, 16B blocks (conflict-free b128).
#define SWZ(row, blk) (((row) << 6) + ((((blk) ^ ((row) & 7))) << 3))

// fast RTNE fp32->bf16 (finite values only)
__device__ __forceinline__ unsigned short f2b(float f) {
    unsigned int u = __float_as_uint(f);
    u += 0x7FFFu + ((u >> 16) & 1u);
    return (unsigned short)(u >> 16);
}

// ---------------------------------------------------------------------------
// Prep: ONE kernel converts x + 4 weights fp32->bf16 and fills the RoPE table.
// ---------------------------------------------------------------------------
__global__ __launch_bounds__(256) void prep_kernel(
    const float* __restrict__ x,  const float* __restrict__ wq,
    const float* __restrict__ wk, const float* __restrict__ wv,
    const float* __restrict__ wo,
    unsigned short* __restrict__ dstbase, float2* __restrict__ rope)
{
    const float* srcs[5] = {x, wq, wk, wv, wo};
    const size_t n4s[5]  = {XN / 4, WN / 4, WN / 4, WN / 4, WN / 4};
    unsigned short* d = dstbase;
    for (int rg = 0; rg < 5; ++rg) {
        const float4* s4 = (const float4*)srcs[rg];
        s16x4* d4 = (s16x4*)d;
        for (size_t i = (size_t)blockIdx.x * 256 + threadIdx.x; i < n4s[rg];
             i += (size_t)gridDim.x * 256) {
            const float4 v = s4[i];
            s16x4 p;
            p.x = (short)f2b(v.x); p.y = (short)f2b(v.y);
            p.z = (short)f2b(v.z); p.w = (short)f2b(v.w);
            d4[i] = p;
        }
        d += n4s[rg] * 4;
    }
    for (int g = blockIdx.x * 256 + threadIdx.x; g < 131072; g += gridDim.x * 256) {
        const int row = g >> 5, fi = g & 31;
        const float invf = expf(-(float)fi * 0.28782313662425576f);
        float sn, cs;
        sincosf((float)row * invf, &sn, &cs);
        rope[row * 32 + fi] = make_float2(cs, sn);
    }
}

// ---------------------------------------------------------------------------
// K1: QKV projection (x @ W.T, MFMA) — unchanged.
// ---------------------------------------------------------------------------
__global__ __launch_bounds__(256) void qkv_mfma(
    const float* __restrict__ x,  const unsigned short* __restrict__ xb,
    const float* __restrict__ Wq, const float* __restrict__ Wk, const float* __restrict__ Wv,
    const unsigned short* __restrict__ Wqb, const unsigned short* __restrict__ Wkb,
    const unsigned short* __restrict__ Wvb,
    const float2* __restrict__ rope,
    unsigned short* __restrict__ Qo, unsigned short* __restrict__ Ko,
    unsigned short* __restrict__ Vo, int fast)
{
    __shared__ __align__(16) unsigned short Xs[2][4096];
    __shared__ __align__(16) unsigned short Ws[2][4096];
    __shared__ unsigned short VL[64 * 66];

    const int t    = threadIdx.x;
    const int w    = t >> 6;
    const int lane = t & 63;
    const int quad = lane >> 4;
    const int l16  = lane & 15;

    const int nt_b = blockIdx.y;
    const float* W; const unsigned short* Wb; int region;
    if (nt_b < 12)      { W = Wq; Wb = Wqb; region = 0; }
    else if (nt_b < 24) { W = Wk; Wb = Wkb; region = 1; }
    else                { W = Wv; Wb = Wvb; region = 2; }
    const int h  = nt_b % 12;
    const int s0 = blockIdx.x * 64;
    const int n0 = h * 64;

    f32x4 acc[4] = {{0,0,0,0},{0,0,0,0},{0,0,0,0},{0,0,0,0}};
    const int prow = t >> 3, pblk = t & 7;

    bf16x8 xr0, xr1, wr0, wr1;
    if (fast) {
        xr0 = *(const bf16x8*)&xb[(size_t)(s0 + prow) * DM + pblk * 8];
        xr1 = *(const bf16x8*)&xb[(size_t)(s0 + prow + 32) * DM + pblk * 8];
        wr0 = *(const bf16x8*)&Wb[(size_t)(n0 + prow) * DM + pblk * 8];
        wr1 = *(const bf16x8*)&Wb[(size_t)(n0 + prow + 32) * DM + pblk * 8];
        *(bf16x8*)&Xs[0][SWZ(prow, pblk)]      = xr0;
        *(bf16x8*)&Xs[0][SWZ(prow + 32, pblk)] = xr1;
        *(bf16x8*)&Ws[0][SWZ(prow, pblk)]      = wr0;
        *(bf16x8*)&Ws[0][SWZ(prow + 32, pblk)] = wr1;
    } else {
        for (int e = t; e < 1024; e += 256) {
            const int row = e >> 4, c4 = e & 15;
            const int off = SWZ(row, c4 >> 1) + (c4 & 1) * 4;
            const float4 xv = *(const float4*)&x[(size_t)(s0 + row) * DM + c4 * 4];
            s16x4 px; px.x = (short)f2b(xv.x); px.y = (short)f2b(xv.y);
            px.z = (short)f2b(xv.z); px.w = (short)f2b(xv.w);
            *(s16x4*)&Xs[0][off] = px;
            const float4 wv = *(const float4*)&W[(size_t)(n0 + row) * DM + c4 * 4];
            s16x4 pw; pw.x = (short)f2b(wv.x); pw.y = (short)f2b(wv.y);
            pw.z = (short)f2b(wv.z); pw.w = (short)f2b(wv.w);
            *(s16x4*)&Ws[0][off] = pw;
        }
    }
    __syncthreads();

    for (int kt = 0; kt < 12; ++kt) {
        const unsigned short* Xb  = Xs[kt & 1];
        const unsigned short* Wbt = Ws[kt & 1];
        if (fast && kt < 11) {
            const int k0 = (kt + 1) * 64;
            xr0 = *(const bf16x8*)&xb[(size_t)(s0 + prow) * DM + k0 + pblk * 8];
            xr1 = *(const bf16x8*)&xb[(size_t)(s0 + prow + 32) * DM + k0 + pblk * 8];
            wr0 = *(const bf16x8*)&Wb[(size_t)(n0 + prow) * DM + k0 + pblk * 8];
            wr1 = *(const bf16x8*)&Wb[(size_t)(n0 + prow + 32) * DM + k0 + pblk * 8];
        }
        const bf16x8 a0 = *(const bf16x8*)&Xb[SWZ(16 * w + l16, quad)];
        const bf16x8 a1 = *(const bf16x8*)&Xb[SWZ(16 * w + l16, 4 + quad)];
        #pragma unroll
        for (int nt = 0; nt < 4; ++nt) {
            const bf16x8 b0 = *(const bf16x8*)&Wbt[SWZ(16 * nt + l16, quad)];
            const bf16x8 b1 = *(const bf16x8*)&Wbt[SWZ(16 * nt + l16, 4 + quad)];
            acc[nt] = MFMA(a0, b0, acc[nt]);
            acc[nt] = MFMA(a1, b1, acc[nt]);
        }
        if (kt < 11) {
            const int nb = (kt + 1) & 1;
            if (fast) {
                *(bf16x8*)&Xs[nb][SWZ(prow, pblk)]      = xr0;
                *(bf16x8*)&Xs[nb][SWZ(prow + 32, pblk)] = xr1;
                *(bf16x8*)&Ws[nb][SWZ(prow, pblk)]      = wr0;
                *(bf16x8*)&Ws[nb][SWZ(prow + 32, pblk)] = wr1;
            } else {
                const int k0 = (kt + 1) * 64;
                for (int e = t; e < 1024; e += 256) {
                    const int row = e >> 4, c4 = e & 15;
                    const int off = SWZ(row, c4 >> 1) + (c4 & 1) * 4;
                    const float4 xv = *(const float4*)&x[(size_t)(s0 + row) * DM + k0 + c4 * 4];
                    s16x4 px; px.x = (short)f2b(xv.x); px.y = (short)f2b(xv.y);
                    px.z = (short)f2b(xv.z); px.w = (short)f2b(xv.w);
                    *(s16x4*)&Xs[nb][off] = px;
                    const float4 wv = *(const float4*)&W[(size_t)(n0 + row) * DM + k0 + c4 * 4];
                    s16x4 pw; pw.x = (short)f2b(wv.x); pw.y = (short)f2b(wv.y);
                    pw.z = (short)f2b(wv.z); pw.w = (short)f2b(wv.w);
                    *(s16x4*)&Ws[nb][off] = pw;
                }
            }
        }
        __syncthreads();
    }

    const size_t headoff = (size_t)h * SEQ * HD;
    if (region <= 1) {
        unsigned short* dst = (region == 0) ? Qo : Ko;
        const float qsc = (region == 0) ? 0.18033688011112042f : 1.0f;   // 0.125*log2e
        #pragma unroll
        for (int nt = 0; nt < 4; ++nt)
            #pragma unroll
            for (int r = 0; r < 4; ++r) {
                const int srow = s0 + 16 * w + quad * 4 + r;
                const int d  = nt * 16 + l16;
                const int fi = d >> 1;
                const float own = acc[nt][r] * qsc;
                const float oth = __shfl_xor(own, 1);
                float cs, sn;
                if (fast) {
                    const float2 t2 = rope[srow * 32 + fi];
                    cs = t2.x; sn = t2.y;
                } else {
                    const float invf = expf(-(float)fi * 0.28782313662425576f);
                    sincosf((float)srow * invf, &sn, &cs);
                }
                const float val = (d & 1) ? (oth * sn + own * cs)
                                          : (own * cs - oth * sn);
                dst[headoff + (size_t)srow * HD + ((d & 1) ? 32 : 0) + fi] = f2b(val);
            }
    } else {
        #pragma unroll
        for (int nt = 0; nt < 4; ++nt)
            #pragma unroll
            for (int r = 0; r < 4; ++r)
                VL[(nt * 16 + l16) * 66 + 16 * w + quad * 4 + r] = f2b(acc[nt][r]);
        __syncthreads();
        for (int e = t; e < 2048; e += 256) {
            const int d = e >> 5, sp = e & 31;
            const unsigned int v = (unsigned int)VL[d * 66 + 2 * sp] |
                                   ((unsigned int)VL[d * 66 + 2 * sp + 1] << 16);
            *(unsigned int*)&Vo[headoff + (size_t)d * SEQ + s0 + 2 * sp] = v;
        }
    }
}

// ---------------------------------------------------------------------------
// K2: causal flash attention — round-0 structure (LDS staging, reg prefetch,
// 2 barriers/chunk) with TWO isolated changes:
//   (1) qt-major QK+exp fusion: exp2/pack of tile qt overlaps QK MFMAs of
//       qt+1 on the separate VALU/MFMA pipes; bK/aV LDS reads hoisted to the
//       top of the chunk so they don't serialize behind P-strip stores.
//   (2) XCD-clustered remap: W=(gid&7)*144+(gid>>3) gives each XCD 1.5
//       consecutive heads (~2MB K/V working set, fits 4MB L2) instead of all
//       12 heads; heavy q-tiles still dispatched first within each XCD.
// ---------------------------------------------------------------------------
__global__ __launch_bounds__(256, 2) void attn_mfma(
    const unsigned short* __restrict__ Q,    // [h][seq][64], pre-scaled
    const unsigned short* __restrict__ K,    // [h][seq][64]
    const unsigned short* __restrict__ V,    // [h][64][seq]  (transposed)
    unsigned short* __restrict__ O,          // [4096][768]
    float* __restrict__ Part)                // [384][2][4160] fp32 partials
{
    __shared__ __align__(16) unsigned char SM[53248];
    unsigned short* Kst = (unsigned short*)SM;             // 128x64 SWZ, 16KB
    unsigned short* Vt  = (unsigned short*)(SM + 16384);   // 64x128 SWZ16, 16KB
    unsigned short* Ps  = (unsigned short*)(SM + 32768);   // 4 strips 64x40, 20KB
    float* ACC  = (float*)SM;
    float* ACC2 = (float*)(SM + 32768);
    float* Lx   = (float*)(SM + 51200);

    // ---- XCD-clustered (head-major) block remap ----
    int h, xx;
    if (gridDim.x == 96) {
        const int gid = blockIdx.y * 96 + blockIdx.x;      // 0..1151
        const int Wl  = (gid & 7) * 144 + (gid >> 3);      // bijective
        h  = Wl / 96;
        xx = Wl - h * 96;
    } else {
        const int gid = blockIdx.y * 64 + blockIdx.x;      // 0..767
        const int Wl  = (gid & 7) * 96 + (gid >> 3);
        h  = Wl >> 6;
        xx = Wl & 63;
    }

    int i, kstart, nch, domask, partial, pslice;
    if (gridDim.x == 96) {
        if (xx < 64) {
            i = 63 - xx; kstart = 0;
            const int full = ((i * 64 + 63) >> 7) + 1;
            nch = full < 16 ? full : 16;
            domask  = (i <= 31);
            partial = (i >= 32); pslice = 0;
        } else {
            i = 127 - xx; kstart = 2048;
            nch = ((i * 64 + 63 - 2048) >> 7) + 1;
            domask = 1; partial = 1; pslice = 1;
        }
    } else {
        i = 63 - xx; kstart = 0;
        nch = ((i * 64 + 63) >> 7) + 1;
        domask = 1; partial = 0; pslice = 0;
    }
    const int q0 = i * 64;

    const int t    = threadIdx.x;
    const int w    = t >> 6;
    const int lane = t & 63;
    const int quad = lane >> 4;
    const int l16  = lane & 15;
    const size_t headoff = (size_t)h * SEQ * HD;

    // ---- stage Q (SWZ64) into Kst, read A-frags for all 64 rows ----
    for (int e = t; e < 512; e += 256) {
        const int row = e >> 3, bp = e & 7, blk = bp ^ (row & 7);
        *(bf16x8*)&Kst[row * 64 + bp * 8] =
            *(const bf16x8*)&Q[headoff + (size_t)(q0 + row) * HD + blk * 8];
    }
    __syncthreads();
    bf16x8 aQ[4][2];
    #pragma unroll
    for (int qt = 0; qt < 4; ++qt)
        #pragma unroll
        for (int hh = 0; hh < 2; ++hh)
            aQ[qt][hh] = *(const bf16x8*)&Kst[SWZ(16 * qt + l16, 4 * hh + quad)];
    __syncthreads();

    // ---- stage chunk 0 (keys kstart..kstart+127) ----
    bf16x8 kreg[4], vreg[4];
    #pragma unroll
    for (int ii = 0; ii < 4; ++ii) {
        const int e = t + ii * 256, row = e >> 3, bp = e & 7, blk = bp ^ (row & 7);
        kreg[ii] = *(const bf16x8*)&K[headoff + (size_t)(kstart + row) * HD + blk * 8];
    }
    #pragma unroll
    for (int ii = 0; ii < 4; ++ii) {
        const int e = t + ii * 256, row = e >> 4, bp = e & 15, blk = bp ^ (row & 15);
        vreg[ii] = *(const bf16x8*)&V[headoff + (size_t)row * SEQ + kstart + blk * 8];
    }
    #pragma unroll
    for (int ii = 0; ii < 4; ++ii) {
        const int e = t + ii * 256, row = e >> 3, bp = e & 7;
        *(bf16x8*)&Kst[row * 64 + bp * 8] = kreg[ii];
    }
    #pragma unroll
    for (int ii = 0; ii < 4; ++ii) {
        const int e = t + ii * 256, row = e >> 4, bp = e & 15;
        *(bf16x8*)&Vt[row * 128 + bp * 8] = vreg[ii];
    }
    __syncthreads();

    bf16x8 ones;
    #pragma unroll
    for (int ii = 0; ii < 8; ++ii) ones[ii] = (short)0x3F80;

    f32x4 oT[4][4];
    #pragma unroll
    for (int dt = 0; dt < 4; ++dt)
        #pragma unroll
        for (int qt = 0; qt < 4; ++qt) oT[dt][qt] = (f32x4){0,0,0,0};
    f32x4 lT[4] = {{0,0,0,0},{0,0,0,0},{0,0,0,0},{0,0,0,0}};

    unsigned short* usp = Ps + w * 2560;

    for (int c = 0; c < nch; ++c) {
        const int k0 = kstart + c * 128;
        const int last = (c == nch - 1);

        // ---- operand preloads from LDS (independent of P strips) ----
        bf16x8 bK[2][2];
        #pragma unroll
        for (int kt = 0; kt < 2; ++kt)
            #pragma unroll
            for (int hh = 0; hh < 2; ++hh)
                bK[kt][hh] = *(const bf16x8*)
                    &Kst[SWZ(32 * w + 16 * kt + l16, 4 * hh + quad)];
        bf16x8 aV[4];
        #pragma unroll
        for (int dt = 0; dt < 4; ++dt) {
            const int row = 16 * dt + l16;
            aV[dt] = *(const bf16x8*)&Vt[row * 128 + (((4 * w + quad) ^ (row & 15)) << 3)];
        }

        // ---- global prefetch of next chunk (full PV phase + barrier of cover)
        if (c + 1 < nch) {
            const int kn = k0 + 128;
            #pragma unroll
            for (int ii = 0; ii < 4; ++ii) {
                const int e = t + ii * 256, row = e >> 3, bp = e & 7, blk = bp ^ (row & 7);
                kreg[ii] = *(const bf16x8*)&K[headoff + (size_t)(kn + row) * HD + blk * 8];
            }
            #pragma unroll
            for (int ii = 0; ii < 4; ++ii) {
                const int e = t + ii * 256, row = e >> 4, bp = e & 15, blk = bp ^ (row & 15);
                vreg[ii] = *(const bf16x8*)&V[headoff + (size_t)row * SEQ + kn + blk * 8];
            }
        }

        // ---- qt-major QK + mask + exp2 + P store (MFMA(qt+1) ∥ VALU(qt)) ----
        #pragma unroll
        for (int qt = 0; qt < 4; ++qt) {
            f32x4 s0 = (f32x4){0,0,0,0}, s1 = (f32x4){0,0,0,0};
            #pragma unroll
            for (int hh = 0; hh < 2; ++hh) {
                s0 = MFMA(aQ[qt][hh], bK[0][hh], s0);
                s1 = MFMA(aQ[qt][hh], bK[1][hh], s1);
            }
            if (domask && last) {
                const int key0 = k0 + 32 * w + l16;
                #pragma unroll
                for (int r = 0; r < 4; ++r) {
                    const int qrow = q0 + 16 * qt + 4 * quad + r;
                    if (key0 > qrow)      s0[r] = -1e30f;
                    if (key0 + 16 > qrow) s1[r] = -1e30f;
                }
            }
            #pragma unroll
            for (int r = 0; r < 4; ++r) {
                const int row = (16 * qt + 4 * quad + r) * 40;
                usp[row + l16]      = f2b(EXP2(s0[r]));
                usp[row + 16 + l16] = f2b(EXP2(s1[r]));
            }
        }

        asm volatile("s_waitcnt lgkmcnt(0)" ::: "memory");

        // ---- PV + row-sum ----
        __builtin_amdgcn_s_setprio(1);
        #pragma unroll
        for (int qt = 0; qt < 4; ++qt) {
            const bf16x8 bP = *(const bf16x8*)&usp[(16 * qt + l16) * 40 + quad * 8];
            lT[qt] = MFMA(ones, bP, lT[qt]);
            #pragma unroll
            for (int dt = 0; dt < 4; ++dt)
                oT[dt][qt] = MFMA(aV[dt], bP, oT[dt][qt]);
        }
        __builtin_amdgcn_s_setprio(0);

        __syncthreads();
        if (c + 1 < nch) {
            #pragma unroll
            for (int ii = 0; ii < 4; ++ii) {
                const int e = t + ii * 256, row = e >> 3, bp = e & 7;
                *(bf16x8*)&Kst[row * 64 + bp * 8] = kreg[ii];
            }
            #pragma unroll
            for (int ii = 0; ii < 4; ++ii) {
                const int e = t + ii * 256, row = e >> 4, bp = e & 15;
                *(bf16x8*)&Vt[row * 128 + bp * 8] = vreg[ii];
            }
        }
        __syncthreads();
    }

    // ---- cross-wave reduction of O^T and l ----
    if (w != 0 && quad == 0) {
        #pragma unroll
        for (int qt = 0; qt < 4; ++qt)
            Lx[w * 64 + 16 * qt + l16] = lT[qt][0];
    }
    if (w == 1) {
        #pragma unroll
        for (int dt = 0; dt < 4; ++dt)
            #pragma unroll
            for (int qt = 0; qt < 4; ++qt)
                *(f32x4*)&ACC[(16 * qt + l16) * 72 + 16 * dt + 4 * quad] = oT[dt][qt];
    }
    __syncthreads();
    if (w == 0) {
        #pragma unroll
        for (int dt = 0; dt < 4; ++dt)
            #pragma unroll
            for (int qt = 0; qt < 4; ++qt)
                oT[dt][qt] += *(const f32x4*)&ACC[(16 * qt + l16) * 72 + 16 * dt + 4 * quad];
    }
    if (w == 2) {
        #pragma unroll
        for (int dt = 0; dt < 4; ++dt)
            #pragma unroll
            for (int qt = 0; qt < 4; ++qt)
                *(f32x4*)&ACC2[(16 * qt + l16) * 72 + 16 * dt + 4 * quad] = oT[dt][qt];
    }
    __syncthreads();
    if (w == 0) {
        #pragma unroll
        for (int dt = 0; dt < 4; ++dt)
            #pragma unroll
            for (int qt = 0; qt < 4; ++qt)
                oT[dt][qt] += *(const f32x4*)&ACC2[(16 * qt + l16) * 72 + 16 * dt + 4 * quad];
    }
    if (w == 3) {
        #pragma unroll
        for (int dt = 0; dt < 4; ++dt)
            #pragma unroll
            for (int qt = 0; qt < 4; ++qt)
                *(f32x4*)&ACC[(16 * qt + l16) * 72 + 16 * dt + 4 * quad] = oT[dt][qt];
    }
    __syncthreads();
    if (w == 0) {
        float ls[4];
        #pragma unroll
        for (int qt = 0; qt < 4; ++qt) {
            #pragma unroll
            for (int dt = 0; dt < 4; ++dt)
                oT[dt][qt] += *(const f32x4*)&ACC[(16 * qt + l16) * 72 + 16 * dt + 4 * quad];
            ls[qt] = lT[qt][0] + Lx[64 + 16 * qt + l16] +
                     Lx[128 + 16 * qt + l16] + Lx[192 + 16 * qt + l16];
        }
        if (!partial) {
            #pragma unroll
            for (int qt = 0; qt < 4; ++qt) {
                const float inv = 1.0f / ls[qt];
                const size_t rowoff = (size_t)(q0 + 16 * qt + l16) * DM + h * HD;
                #pragma unroll
                for (int dt = 0; dt < 4; ++dt) {
                    ushort4 u;
                    u.x = f2b(oT[dt][qt][0] * inv);
                    u.y = f2b(oT[dt][qt][1] * inv);
                    u.z = f2b(oT[dt][qt][2] * inv);
                    u.w = f2b(oT[dt][qt][3] * inv);
                    *(ushort4*)&O[rowoff + 16 * dt + 4 * quad] = u;
                }
            }
        } else {
            // Partials in [q][d] layout matching the C-fragment:
            // oT[dt][qt][r] = O[q=16qt+l16][d=16dt+4quad+r].
            float* P = Part + (size_t)(((i - 32) * 12 + h) * 2 + pslice) * 4160;
            #pragma unroll
            for (int dt = 0; dt < 4; ++dt)
                #pragma unroll
                for (int qt = 0; qt < 4; ++qt)
                    *(f32x4*)&P[(16 * qt + l16) * 64 + 16 * dt + 4 * quad] = oT[dt][qt];
            if (quad == 0) {
                #pragma unroll
                for (int qt = 0; qt < 4; ++qt)
                    P[4096 + 16 * qt + l16] = ls[qt];
            }
        }
    }
}

// ---------------------------------------------------------------------------
// K2b: combine the two key-slices for q-tiles 32..63, normalize, write O.
// Grid (384): b -> (i = 32 + b/12, h = b%12). Partials are [q][d] fp32.
// ---------------------------------------------------------------------------
__global__ __launch_bounds__(256) void reduce_attn(
    const float* __restrict__ Part, unsigned short* __restrict__ O)
{
    const int b  = blockIdx.x;
    const int i  = 32 + b / 12, h = b % 12;
    const int q0 = i * 64;
    const float* P0 = Part + (size_t)(b * 2 + 0) * 4160;
    const float* P1 = Part + (size_t)(b * 2 + 1) * 4160;
    __shared__ float linv[64];
    const int t = threadIdx.x;
    if (t < 64) linv[t] = 1.0f / (P0[4096 + t] + P1[4096 + t]);
    __syncthreads();
    for (int idx = t; idx < 4096; idx += 256) {
        const int q = idx >> 6, d = idx & 63;
        const float v = (P0[q * 64 + d] + P1[q * 64 + d]) * linv[q];
        O[(size_t)(q0 + q) * DM + h * HD + d] = f2b(v);
    }
}

// ---------------------------------------------------------------------------
// K3: output projection out = A @ Wo.T + bo (MFMA) — unchanged.
// ---------------------------------------------------------------------------
__global__ __launch_bounds__(256) void proj_mfma(
    const unsigned short* __restrict__ A,
    const float* __restrict__ Wo, const unsigned short* __restrict__ Wob,
    const float* __restrict__ bo,
    float* __restrict__ out, int fast)
{
    __shared__ __align__(16) unsigned short Xs[2][4096];
    __shared__ __align__(16) unsigned short Ws[2][4096];

    const int t    = threadIdx.x;
    const int w    = t >> 6;
    const int lane = t & 63;
    const int quad = lane >> 4;
    const int l16  = lane & 15;
    const int s0 = blockIdx.x * 64;
    const int n0 = blockIdx.y * 64;
    const int prow = t >> 3, pblk = t & 7;

    f32x4 acc[4] = {{0,0,0,0},{0,0,0,0},{0,0,0,0},{0,0,0,0}};

    bf16x8 ar0, ar1, wr0, wr1;
    ar0 = *(const bf16x8*)&A[(size_t)(s0 + prow) * DM + pblk * 8];
    ar1 = *(const bf16x8*)&A[(size_t)(s0 + prow + 32) * DM + pblk * 8];
    *(bf16x8*)&Xs[0][SWZ(prow, pblk)]      = ar0;
    *(bf16x8*)&Xs[0][SWZ(prow + 32, pblk)] = ar1;
    if (fast) {
        wr0 = *(const bf16x8*)&Wob[(size_t)(n0 + prow) * DM + pblk * 8];
        wr1 = *(const bf16x8*)&Wob[(size_t)(n0 + prow + 32) * DM + pblk * 8];
        *(bf16x8*)&Ws[0][SWZ(prow, pblk)]      = wr0;
        *(bf16x8*)&Ws[0][SWZ(prow + 32, pblk)] = wr1;
    } else {
        for (int e = t; e < 1024; e += 256) {
            const int row = e >> 4, c4 = e & 15;
            const float4 wv = *(const float4*)&Wo[(size_t)(n0 + row) * DM + c4 * 4];
            s16x4 pw; pw.x = (short)f2b(wv.x); pw.y = (short)f2b(wv.y);
            pw.z = (short)f2b(wv.z); pw.w = (short)f2b(wv.w);
            *(s16x4*)&Ws[0][SWZ(row, c4 >> 1) + (c4 & 1) * 4] = pw;
        }
    }
    __syncthreads();

    for (int kt = 0; kt < 12; ++kt) {
        const unsigned short* Xb  = Xs[kt & 1];
        const unsigned short* Wbt = Ws[kt & 1];
        if (kt < 11) {
            const int k0 = (kt + 1) * 64;
            ar0 = *(const bf16x8*)&A[(size_t)(s0 + prow) * DM + k0 + pblk * 8];
            ar1 = *(const bf16x8*)&A[(size_t)(s0 + prow + 32) * DM + k0 + pblk * 8];
            if (fast) {
                wr0 = *(const bf16x8*)&Wob[(size_t)(n0 + prow) * DM + k0 + pblk * 8];
                wr1 = *(const bf16x8*)&Wob[(size_t)(n0 + prow + 32) * DM + k0 + pblk * 8];
            }
        }
        const bf16x8 a0 = *(const bf16x8*)&Xb[SWZ(16 * w + l16, quad)];
        const bf16x8 a1 = *(const bf16x8*)&Xb[SWZ(16 * w + l16, 4 + quad)];
        #pragma unroll
        for (int nt = 0; nt < 4; ++nt) {
            const bf16x8 b0 = *(const bf16x8*)&Wbt[SWZ(16 * nt + l16, quad)];
            const bf16x8 b1 = *(const bf16x8*)&Wbt[SWZ(16 * nt + l16, 4 + quad)];
            acc[nt] = MFMA(a0, b0, acc[nt]);
            acc[nt] = MFMA(a1, b1, acc[nt]);
        }
        if (kt < 11) {
            const int nb = (kt + 1) & 1;
            *(bf16x8*)&Xs[nb][SWZ(prow, pblk)]      = ar0;
            *(bf16x8*)&Xs[nb][SWZ(prow + 32, pblk)] = ar1;
            if (fast) {
                *(bf16x8*)&Ws[nb][SWZ(prow, pblk)]      = wr0;
                *(bf16x8*)&Ws[nb][SWZ(prow + 32, pblk)] = wr1;
            } else {
                const int k0 = (kt + 1) * 64;
                for (int e = t; e < 1024; e += 256) {
                    const int row = e >> 4, c4 = e & 15;
                    const float4 wv = *(const float4*)&Wo[(size_t)(n0 + row) * DM + k0 + c4 * 4];
                    s16x4 pw; pw.x = (short)f2b(wv.x); pw.y = (short)f2b(wv.y);
                    pw.z = (short)f2b(wv.z); pw.w = (short)f2b(wv.w);
                    *(s16x4*)&Ws[nb][SWZ(row, c4 >> 1) + (c4 & 1) * 4] = pw;
                }
            }
        }
        __syncthreads();
    }

    #pragma unroll
    for (int nt = 0; nt < 4; ++nt)
        #pragma unroll
        for (int r = 0; r < 4; ++r) {
            const int srow = s0 + 16 * w + quad * 4 + r;
            const int n    = n0 + nt * 16 + l16;
            out[(size_t)srow * DM + n] = acc[nt][r] + bo[n];
        }
}

// ---------------------------------------------------------------------------
extern "C" void kernel_launch(void* const* d_in, const int* in_sizes, int n_in,
                              void* d_out, int out_size, void* d_ws, size_t ws_size,
                              hipStream_t stream) {
    const float* x  = (const float*)d_in[0];
    const float* Wq = (const float*)d_in[2];
    const float* Wk = (const float*)d_in[3];
    const float* Wv = (const float*)d_in[4];
    const float* Wo = (const float*)d_in[5];
    const float* bo = (const float*)d_in[6];
    float* out = (float*)d_out;

    unsigned short* U  = (unsigned short*)d_ws;
    unsigned short* Qw = U;
    unsigned short* Kw = U + PER;
    unsigned short* Vw = U + 2 * PER;    // transposed [h][64][seq]
    unsigned short* Ow = U + 3 * PER;    // [4096][768]
    unsigned short* xb  = U + 4 * PER;
    unsigned short* Wqb = xb + XN;
    unsigned short* Wkb = Wqb + WN;
    unsigned short* Wvb = Wkb + WN;
    unsigned short* Wob = Wvb + WN;
    float2* rope = (float2*)(Wob + WN);  // [4096][32]
    float*  part = (float*)(rope + 4096 * 32);   // [384][2][4160] fp32
    const size_t need  = (char*)part - (char*)d_ws;
    const size_t need2 = need + (size_t)384 * 2 * 4160 * 4;
    const int fast  = (ws_size >= need)  ? 1 : 0;
    const int split = (ws_size >= need2) ? 1 : 0;

    if (fast)
        prep_kernel<<<1024, 256, 0, stream>>>(x, Wq, Wk, Wv, Wo, xb, rope);
    qkv_mfma<<<dim3(SEQ / 64, 36), 256, 0, stream>>>(
        x, xb, Wq, Wk, Wv, Wqb, Wkb, Wvb, rope, Qw, Kw, Vw, fast);
    if (split) {
        attn_mfma<<<dim3(96, NH), 256, 0, stream>>>(Qw, Kw, Vw, Ow, part);
        reduce_attn<<<dim3(384), 256, 0, stream>>>(part, Ow);
    } else {
        attn_mfma<<<dim3(64, NH), 256, 0, stream>>>(Qw, Kw, Vw, Ow, part);
    }
    proj_mfma<<<dim3(SEQ / 64, DM / 64), 256, 0, stream>>>(Ow, Wo, Wob, bo, out, fast);
}